// Round 8
// baseline (432.077 us; speedup 1.0000x reference)
//
#include <hip/hip_runtime.h>
#include <cmath>
#include <cfloat>

#define DEV __device__ __forceinline__

DEV unsigned enc_f(float x) { unsigned u = __float_as_uint(x); return (u >> 31) ? ~u : (u | 0x80000000u); }
DEV float dec_f(unsigned u) { return __uint_as_float((u >> 31) ? (u & 0x7FFFFFFFu) : ~u); }

// ---------------- XCD-partitioned degree count (+ encoder in last block) ----------------
__global__ __launch_bounds__(256) void enc_count_kernel(
    const int* __restrict__ dst, int* __restrict__ deg, int E, int N, int nCount,
    const int* __restrict__ ids, const float* __restrict__ rssi,
    const float* __restrict__ emb, const float* __restrict__ ew, const float* __restrict__ eb,
    const float* __restrict__ Wl0, const float* __restrict__ Wr0, const float* __restrict__ b0,
    float* __restrict__ zout, int NQ)
{
    if (blockIdx.x < (unsigned)nCount) {
        const int part = blockIdx.x & 7;
        const int chunk = blockIdx.x >> 3;
        const int npart = (N + 7) >> 3;
        const int lo = part * npart;
        const int hi = min(lo + npart, N);
        const int base = chunk * 4096 + threadIdx.x;
#pragma unroll
        for (int it = 0; it < 16; ++it) {
            int i = base + it * 256;
            if (i < E) {
                int d = dst[i];
                if (d >= lo && d < hi) atomicAdd(&deg[d], 1);
            }
        }
        return;
    }
    __shared__ float zsh[4][64];
    __shared__ float zq[64];
    int j = threadIdx.x & 63;
    int g = threadIdx.x >> 6;
    float acc = 0.f;
    for (int q = g; q < NQ; q += 4) {
        int id = ids[q];
        const float* e = emb + (size_t)id * 32;
        float p = eb[j];
#pragma unroll
        for (int k = 0; k < 32; ++k) p = fmaf(e[k], ew[k * 64 + j], p);
        p = fmaf(rssi[q], ew[32 * 64 + j], p);
        acc += fmaxf(p, 0.f);
    }
    zsh[g][j] = acc;
    __syncthreads();
    if (g == 0) {
        float z = (zsh[0][j] + zsh[1][j] + zsh[2][j] + zsh[3][j]) / (float)NQ;
        zq[j] = z;
        zout[j] = z;
    }
    __syncthreads();
    if (g == 0) {
        float cl = 0.f, cr = 0.f;
        for (int k = 0; k < 64; ++k) {
            float zk = zq[k];
            cl = fmaf(zk, Wl0[(128 + k) * 64 + j], cl);
            cr = fmaf(zk, Wr0[(128 + k) * 64 + j], cr);
        }
        zout[64 + j] = cl;
        zout[128 + j] = cr + b0[j];
    }
}

// ---------------- CSR build: multi-block scan ----------------
__global__ __launch_bounds__(256) void scanA_kernel(const int* __restrict__ deg, int* __restrict__ offs,
                                                    int* __restrict__ bsum, int N)
{
    __shared__ int sh[256];
    int t = threadIdx.x;
    int i = blockIdx.x * 256 + t;
    int v = (i < N) ? deg[i] : 0;
    sh[t] = v;
    __syncthreads();
#pragma unroll
    for (int d = 1; d < 256; d <<= 1) {
        int u = (t >= d) ? sh[t - d] : 0;
        __syncthreads();
        sh[t] += u;
        __syncthreads();
    }
    if (i < N) offs[i] = sh[t] - v;
    if (t == 255) bsum[blockIdx.x] = sh[255];
}

__global__ __launch_bounds__(256) void scanB_kernel(const int* __restrict__ bsum, int* __restrict__ bbase,
                                                    int* __restrict__ offs, unsigned* __restrict__ red,
                                                    int NB, int N)
{
    __shared__ int sh[256];
    int t = threadIdx.x;
    if (t < 4) red[t] = 0u;
    int C = (NB + 255) >> 8;
    int c0 = t * C, c1 = min(c0 + C, NB);
    int s = 0;
    for (int i = c0; i < c1; ++i) s += bsum[i];
    sh[t] = s;
    __syncthreads();
#pragma unroll
    for (int d = 1; d < 256; d <<= 1) {
        int u = (t >= d) ? sh[t - d] : 0;
        __syncthreads();
        sh[t] += u;
        __syncthreads();
    }
    int run = (t > 0) ? sh[t - 1] : 0;
    for (int i = c0; i < c1; ++i) { bbase[i] = run; run += bsum[i]; }
    if (t == 255) offs[N] = sh[255];
}

__global__ __launch_bounds__(256) void scanC_kernel(int* __restrict__ offs, int* __restrict__ cursor,
                                                    const int* __restrict__ bbase, int N)
{
    int i = blockIdx.x * 256 + threadIdx.x;
    if (i < N) {
        int o = offs[i] + bbase[blockIdx.x];
        offs[i] = o;
        cursor[i] = o;
    }
}

// XCD-partitioned scatter (round-2 win): one XCD owns each srcs region.
__global__ __launch_bounds__(256) void scatter_kernel(const int* __restrict__ src, const int* __restrict__ dst,
                                                      int* __restrict__ cursor, int* __restrict__ srcs,
                                                      int E, int N)
{
    const int part = blockIdx.x & 7;
    const int chunk = blockIdx.x >> 3;
    const int npart = (N + 7) >> 3;
    const int lo = part * npart;
    const int hi = min(lo + npart, N);
    const int base = chunk * 4096 + threadIdx.x;
#pragma unroll
    for (int it = 0; it < 16; ++it) {
        int i = base + it * 256;
        if (i < E) {
            int d = dst[i];
            if (d >= lo && d < hi) {
                int p = atomicAdd(&cursor[d], 1);
                srcs[p] = src[i];
            }
        }
    }
}

// ---------------- layer-0 GEMM (K=128, dual out): O1 = x@B1, O2 = x@B2 + add2 ----------------
// A is NOT staged in LDS: each half-wave's 32 lanes load the same A[row][k..k+3] float4
// (one 16B request, broadcast). Kills the 3M 16-way bank conflicts of the transposed
// A-staging and halves LDS traffic (only the Bs spread-read remains) -> VALU-bound.
__global__ __launch_bounds__(256) void gemm0_kernel(
    const float* __restrict__ A, const float* __restrict__ B1, const float* __restrict__ B2,
    const float* __restrict__ add2,
    float* __restrict__ O1, float* __restrict__ O2, int N)
{
    constexpr int K = 128;
    __shared__ float Bs[32][128];   // 16.4 KB only

    const int tid = threadIdx.x;
    const int cg = tid & 31;
    const int rg = tid >> 5;
    const int row0 = blockIdx.x * 64;

    // per-row clamped byte-offset bases (8 rows per thread)
    const float* arow[8];
#pragma unroll
    for (int i = 0; i < 8; ++i)
        arow[i] = A + (size_t)min(row0 + rg * 8 + i, N - 1) * K;

    float acc[8][4];
#pragma unroll
    for (int i = 0; i < 8; ++i)
#pragma unroll
        for (int j = 0; j < 4; ++j) acc[i][j] = 0.f;

    for (int kc = 0; kc < K; kc += 32) {
#pragma unroll
        for (int i = 0; i < 4; ++i) {
            int vi = i * 256 + tid;
            int k = vi >> 5;
            int c = (vi & 31) << 2;
            const float* sp = (c < 64) ? (B1 + (size_t)(kc + k) * 64 + c)
                                       : (B2 + (size_t)(kc + k) * 64 + (c - 64));
            *(float4*)&Bs[k][c] = *(const float4*)sp;
        }
        __syncthreads();
#pragma unroll
        for (int k4 = 0; k4 < 32; k4 += 4) {
            float4 a4[8];
#pragma unroll
            for (int i = 0; i < 8; ++i)
                a4[i] = *(const float4*)(arow[i] + kc + k4);
            float4 bv[4];
#pragma unroll
            for (int j = 0; j < 4; ++j)
                bv[j] = *(const float4*)&Bs[k4 + j][cg * 4];
#pragma unroll
            for (int j = 0; j < 4; ++j) {
#pragma unroll
                for (int i = 0; i < 8; ++i) {
                    float av = ((const float*)&a4[i])[j];
                    acc[i][0] = fmaf(av, bv[j].x, acc[i][0]);
                    acc[i][1] = fmaf(av, bv[j].y, acc[i][1]);
                    acc[i][2] = fmaf(av, bv[j].z, acc[i][2]);
                    acc[i][3] = fmaf(av, bv[j].w, acc[i][3]);
                }
            }
        }
        __syncthreads();
    }

    int c0 = cg * 4;
    float* O; int c; const float* addp;
    if (c0 < 64) { O = O1; c = c0; addp = nullptr; }
    else         { O = O2; c = c0 - 64; addp = add2; }
    float4 av = make_float4(0.f, 0.f, 0.f, 0.f);
    if (addp) av = *(const float4*)(addp + c);
#pragma unroll
    for (int i = 0; i < 8; ++i) {
        int row = row0 + rg * 8 + i;
        if (row < N) {
            float4 o;
            o.x = acc[i][0] + av.x; o.y = acc[i][1] + av.y;
            o.z = acc[i][2] + av.z; o.w = acc[i][3] + av.w;
            *(float4*)(O + (size_t)row * 64 + c) = o;
        }
    }
}

// ---------------- K=64 dual GEMM: B in LDS (one stage + one sync), A from global ----------------
__global__ __launch_bounds__(256) void gemm64_kernel(
    const float* __restrict__ A, const float* __restrict__ B1, const float* __restrict__ B2,
    const float* __restrict__ add2,
    float* __restrict__ O1, float* __restrict__ O2, int N)
{
    __shared__ float Bs[64][128];   // 32.8 KB

    const int tid = threadIdx.x;
    const int cg = tid & 31;
    const int rg = tid >> 5;
    const int row0 = blockIdx.x * 64;

    const float* arow[8];
#pragma unroll
    for (int i = 0; i < 8; ++i)
        arow[i] = A + (size_t)min(row0 + rg * 8 + i, N - 1) * 64;

#pragma unroll
    for (int i = 0; i < 8; ++i) {
        int vi = i * 256 + tid;
        int k = vi >> 5;
        int c = (vi & 31) << 2;
        const float* sp = (c < 64) ? (B1 + (size_t)k * 64 + c)
                                   : (B2 + (size_t)k * 64 + (c - 64));
        *(float4*)&Bs[k][c] = *(const float4*)sp;
    }
    __syncthreads();

    float acc[8][4];
#pragma unroll
    for (int i = 0; i < 8; ++i)
#pragma unroll
        for (int j = 0; j < 4; ++j) acc[i][j] = 0.f;

#pragma unroll 4
    for (int k4 = 0; k4 < 64; k4 += 4) {
        float4 a4[8];
#pragma unroll
        for (int i = 0; i < 8; ++i)
            a4[i] = *(const float4*)(arow[i] + k4);
        float4 bv[4];
#pragma unroll
        for (int j = 0; j < 4; ++j)
            bv[j] = *(const float4*)&Bs[k4 + j][cg * 4];
#pragma unroll
        for (int j = 0; j < 4; ++j) {
#pragma unroll
            for (int i = 0; i < 8; ++i) {
                float av = ((const float*)&a4[i])[j];
                acc[i][0] = fmaf(av, bv[j].x, acc[i][0]);
                acc[i][1] = fmaf(av, bv[j].y, acc[i][1]);
                acc[i][2] = fmaf(av, bv[j].z, acc[i][2]);
                acc[i][3] = fmaf(av, bv[j].w, acc[i][3]);
            }
        }
    }

    int c0 = cg * 4;
    float* O; int c; const float* addp;
    if (c0 < 64) { O = O1; c = c0; addp = nullptr; }
    else         { O = O2; c = c0 - 64; addp = add2; }
    float4 av = make_float4(0.f, 0.f, 0.f, 0.f);
    if (addp) av = *(const float4*)(addp + c);
#pragma unroll
    for (int i = 0; i < 8; ++i) {
        int row = row0 + rg * 8 + i;
        if (row < N) {
            float4 o;
            o.x = acc[i][0] + av.x; o.y = acc[i][1] + av.y;
            o.z = acc[i][2] + av.z; o.w = acc[i][3] + av.w;
            *(float4*)(O + (size_t)row * 64 + c) = o;
        }
    }
}

// ---------------- aggregation: h = relu(segsum(m)/clip(deg,1) + [deg>0]*cl + r) ----------------
__global__ __launch_bounds__(256) void agg_kernel(
    const float* __restrict__ m, const float* __restrict__ r,
    const int* __restrict__ off, const int* __restrict__ srcs,
    const float* __restrict__ cl, float* __restrict__ hout, int N)
{
    int node = blockIdx.x * 4 + threadIdx.y;
    if (node >= N) return;
    int lane = threadIdx.x;
    int e0 = off[node], e1 = off[node + 1];
    float a[16];
#pragma unroll
    for (int i = 0; i < 16; ++i) a[i] = 0.f;

    for (int base = e0; base < e1; base += 64) {
        int e = base + lane;
        int sv = (e < e1) ? srcs[e] : 0;
        int cnt = min(e1 - base, 64);
        int j = 0;
        for (; j + 16 <= cnt; j += 16) {
#pragma unroll
            for (int u = 0; u < 16; ++u) {
                int s = __shfl(sv, j + u);
                a[u] += m[(size_t)s * 64 + lane];
            }
        }
        for (; j + 4 <= cnt; j += 4) {
#pragma unroll
            for (int u = 0; u < 4; ++u) {
                int s = __shfl(sv, j + u);
                a[u] += m[(size_t)s * 64 + lane];
            }
        }
        for (; j < cnt; ++j) {
            int s = __shfl(sv, j);
            a[0] += m[(size_t)s * 64 + lane];
        }
    }
    float sum = 0.f;
#pragma unroll
    for (int i = 0; i < 16; ++i) sum += a[i];
    int deg = e1 - e0;
    float v = sum / (float)(deg > 0 ? deg : 1) + r[(size_t)node * 64 + lane];
    if (cl != nullptr && deg > 0) v += cl[lane];
    hout[(size_t)node * 64 + lane] = fmaxf(v, 0.f);
}

// ---------------- fused scorer: s = relu(h@w1+b1)@w2 + b2, block max -> atomicMax ----------------
__global__ __launch_bounds__(256) void scorer_gemm_kernel(
    const float* __restrict__ A, const float* __restrict__ B1,
    const float* __restrict__ bias, const float* __restrict__ w2, const float* __restrict__ b2,
    float* __restrict__ sbuf, unsigned* __restrict__ red, int N)
{
    __shared__ float Bs[64][64];
    __shared__ float smax[256];

    const int tid = threadIdx.x;
    const int cg = tid & 31;
    const int rg = tid >> 5;
    const int row0 = blockIdx.x * 64;

    const float* arow[8];
#pragma unroll
    for (int i = 0; i < 8; ++i)
        arow[i] = A + (size_t)min(row0 + rg * 8 + i, N - 1) * 64;

#pragma unroll
    for (int i = 0; i < 4; ++i) {
        int vi = i * 256 + tid;
        int k = vi >> 4;
        int c = (vi & 15) << 2;
        *(float4*)&Bs[k][c] = *(const float4*)(B1 + (size_t)k * 64 + c);
    }
    __syncthreads();

    float acc[8][2];
#pragma unroll
    for (int i = 0; i < 8; ++i) { acc[i][0] = 0.f; acc[i][1] = 0.f; }

#pragma unroll 4
    for (int k4 = 0; k4 < 64; k4 += 4) {
        float4 a4[8];
#pragma unroll
        for (int i = 0; i < 8; ++i)
            a4[i] = *(const float4*)(arow[i] + k4);
        float2 bv[4];
#pragma unroll
        for (int j = 0; j < 4; ++j)
            bv[j] = *(const float2*)&Bs[k4 + j][cg * 2];
#pragma unroll
        for (int j = 0; j < 4; ++j) {
#pragma unroll
            for (int i = 0; i < 8; ++i) {
                float av = ((const float*)&a4[i])[j];
                acc[i][0] = fmaf(av, bv[j].x, acc[i][0]);
                acc[i][1] = fmaf(av, bv[j].y, acc[i][1]);
            }
        }
    }

    float2 av = *(const float2*)(bias + cg * 2);
    float w0 = w2[cg * 2], w1 = w2[cg * 2 + 1];
    float bb = b2[0];
    float svals[8];
#pragma unroll
    for (int i = 0; i < 8; ++i) {
        float t0 = fmaxf(acc[i][0] + av.x, 0.f);
        float t1 = fmaxf(acc[i][1] + av.y, 0.f);
        float p = fmaf(t0, w0, t1 * w1);
#pragma unroll
        for (int d = 16; d >= 1; d >>= 1) p += __shfl_xor(p, d, 64);
        svals[i] = p;
    }
    float smx = -FLT_MAX;
    if (cg == 0) {
#pragma unroll
        for (int i = 0; i < 8; ++i) {
            int row = row0 + rg * 8 + i;
            if (row < N) {
                float s = svals[i] + bb;
                sbuf[row] = s;
                smx = fmaxf(smx, s);
            }
        }
    }
    smax[tid] = smx;
    __syncthreads();
    for (int d = 128; d >= 1; d >>= 1) {
        if (tid < d) smax[tid] = fmaxf(smax[tid], smax[tid + d]);
        __syncthreads();
    }
    if (tid == 0) atomicMax(red, enc_f(smax[0]));
}

// ---------------- softmax reductions ----------------
__global__ __launch_bounds__(256) void sum_kernel(const float* __restrict__ s, const float* __restrict__ pos,
                                                  const unsigned* __restrict__ redmax, float* __restrict__ red, int N)
{
    float mx = dec_f(redmax[0]);
    float se = 0.f, px = 0.f, py = 0.f;
    for (int i = blockIdx.x * blockDim.x + threadIdx.x; i < N; i += gridDim.x * blockDim.x) {
        float e = expf(s[i] - mx);
        se += e;
        px = fmaf(e, pos[2 * i], px);
        py = fmaf(e, pos[2 * i + 1], py);
    }
#pragma unroll
    for (int d = 32; d >= 1; d >>= 1) {
        se += __shfl_xor(se, d, 64);
        px += __shfl_xor(px, d, 64);
        py += __shfl_xor(py, d, 64);
    }
    if ((threadIdx.x & 63) == 0) {
        atomicAdd(&red[1], se);
        atomicAdd(&red[2], px);
        atomicAdd(&red[3], py);
    }
}

__global__ __launch_bounds__(256) void final_kernel(const float* __restrict__ s, const unsigned* __restrict__ redmax,
                                                    const float* __restrict__ red, float* __restrict__ out, int N)
{
    float mx = dec_f(redmax[0]);
    float S = red[1];
    int i = blockIdx.x * blockDim.x + threadIdx.x;
    if (i < N) out[2 + i] = expf(s[i] - mx) / S;
    if (i == 0) {
        out[0] = red[2] / S;
        out[1] = red[3] / S;
    }
}

extern "C" void kernel_launch(void* const* d_in, const int* in_sizes, int n_in,
                              void* d_out, int out_size, void* d_ws, size_t ws_size,
                              hipStream_t stream)
{
    const float* x    = (const float*)d_in[0];
    const float* pos  = (const float*)d_in[1];
    const int*   ei   = (const int*)d_in[2];
    const int*   qids = (const int*)d_in[3];
    const float* qrs  = (const float*)d_in[4];
    const float* emb  = (const float*)d_in[5];
    const float* ew   = (const float*)d_in[6];
    const float* eb   = (const float*)d_in[7];
    const float* Wl0  = (const float*)d_in[8];
    const float* Wr0  = (const float*)d_in[9];
    const float* b0   = (const float*)d_in[10];
    const float* Wl1  = (const float*)d_in[11];
    const float* Wr1  = (const float*)d_in[12];
    const float* b1   = (const float*)d_in[13];
    const float* Wl2  = (const float*)d_in[14];
    const float* Wr2  = (const float*)d_in[15];
    const float* b2   = (const float*)d_in[16];
    const float* sw1  = (const float*)d_in[17];
    const float* sb1  = (const float*)d_in[18];
    const float* sw2  = (const float*)d_in[19];
    const float* sb2  = (const float*)d_in[20];

    const int N  = in_sizes[0] / 128;
    const int E  = in_sizes[2] / 2;
    const int NQ = in_sizes[3];
    const int NB = (N + 255) / 256;

    char* base = (char*)d_ws;
    size_t wsoff = 0;
    auto take = [&](size_t bytes) -> char* {
        char* p = base + wsoff;
        wsoff = (wsoff + bytes + 255) & ~(size_t)255;
        return p;
    };
    int*      deg    = (int*)take((size_t)N * 4);
    int*      offs   = (int*)take((size_t)(N + 1) * 4);
    int*      cursor = (int*)take((size_t)N * 4);
    int*      bsum   = (int*)take((size_t)NB * 4);
    int*      bbase  = (int*)take((size_t)NB * 4);
    int*      srcs   = (int*)take((size_t)E * 4);
    float*    zout   = (float*)take(192 * 4);   // zq[64], cl[64], crb[64]
    unsigned* red    = (unsigned*)take(16);     // [0]=max(enc) [1]=sumexp [2]=px [3]=py
    float*    mbuf   = (float*)take((size_t)N * 64 * 4);
    float*    rbuf   = (float*)take((size_t)N * 64 * 4);
    float*    hbuf   = (float*)take((size_t)N * 64 * 4);
    float*    sbuf   = (float*)take((size_t)N * 4);
    (void)ws_size; (void)n_in; (void)out_size;

    const int* esrc = ei;
    const int* edst = ei + E;

    hipMemsetAsync(deg, 0, (size_t)N * 4, stream);

    int schunks = (E + 4095) / 4096;
    int nCount = schunks * 8;
    enc_count_kernel<<<nCount + 1, 256, 0, stream>>>(edst, deg, E, N, nCount,
                                                     qids, qrs, emb, ew, eb, Wl0, Wr0, b0, zout, NQ);
    scanA_kernel<<<NB, 256, 0, stream>>>(deg, offs, bsum, N);
    scanB_kernel<<<1, 256, 0, stream>>>(bsum, bbase, offs, red, NB, N);
    scanC_kernel<<<NB, 256, 0, stream>>>(offs, cursor, bbase, N);
    scatter_kernel<<<schunks * 8, 256, 0, stream>>>(esrc, edst, cursor, srcs, E, N);

    int gblocks = (N + 63) / 64;
    dim3 ablk(64, 4);
    int ablocks = (N + 3) / 4;

    // layer 0: mbuf = x@Wl0_top, rbuf = x@Wr0_top + (zq@Wr0_bot + b0)
    gemm0_kernel<<<gblocks, 256, 0, stream>>>(x, Wl0, Wr0, zout + 128, mbuf, rbuf, N);
    agg_kernel<<<ablocks, ablk, 0, stream>>>(mbuf, rbuf, offs, srcs, zout + 64, hbuf, N);
    // layer 1
    gemm64_kernel<<<gblocks, 256, 0, stream>>>(hbuf, Wl1, Wr1, b1, mbuf, rbuf, N);
    agg_kernel<<<ablocks, ablk, 0, stream>>>(mbuf, rbuf, offs, srcs, nullptr, hbuf, N);
    // layer 2
    gemm64_kernel<<<gblocks, 256, 0, stream>>>(hbuf, Wl2, Wr2, b2, mbuf, rbuf, N);
    agg_kernel<<<ablocks, ablk, 0, stream>>>(mbuf, rbuf, offs, srcs, nullptr, hbuf, N);
    // fused scorer (writes sbuf + atomicMax into red[0])
    scorer_gemm_kernel<<<gblocks, 256, 0, stream>>>(hbuf, sw1, sb1, sw2, sb2, sbuf, red, N);

    sum_kernel<<<128, 256, 0, stream>>>(sbuf, pos, red, (float*)red, N);
    final_kernel<<<(N + 255) / 256, 256, 0, stream>>>(sbuf, red, (float*)red, (float*)d_out, N);
}

// Round 9
// 398.539 us; speedup vs baseline: 1.0842x; 1.0842x over previous
//
#include <hip/hip_runtime.h>
#include <cmath>
#include <cfloat>

#define DEV __device__ __forceinline__

DEV unsigned enc_f(float x) { unsigned u = __float_as_uint(x); return (u >> 31) ? ~u : (u | 0x80000000u); }
DEV float dec_f(unsigned u) { return __uint_as_float((u >> 31) ? (u & 0x7FFFFFFFu) : ~u); }

// ---------------- XCD-partitioned degree count (+ encoder in last block) ----------------
__global__ __launch_bounds__(256) void enc_count_kernel(
    const int* __restrict__ dst, int* __restrict__ deg, int E, int N, int nCount,
    const int* __restrict__ ids, const float* __restrict__ rssi,
    const float* __restrict__ emb, const float* __restrict__ ew, const float* __restrict__ eb,
    const float* __restrict__ Wl0, const float* __restrict__ Wr0, const float* __restrict__ b0,
    float* __restrict__ zout, int NQ)
{
    if (blockIdx.x < (unsigned)nCount) {
        const int part = blockIdx.x & 7;
        const int chunk = blockIdx.x >> 3;
        const int npart = (N + 7) >> 3;
        const int lo = part * npart;
        const int hi = min(lo + npart, N);
        const int base = chunk * 4096 + threadIdx.x;
#pragma unroll
        for (int it = 0; it < 16; ++it) {
            int i = base + it * 256;
            if (i < E) {
                int d = dst[i];
                if (d >= lo && d < hi) atomicAdd(&deg[d], 1);
            }
        }
        return;
    }
    __shared__ float zsh[4][64];
    __shared__ float zq[64];
    int j = threadIdx.x & 63;
    int g = threadIdx.x >> 6;
    float acc = 0.f;
    for (int q = g; q < NQ; q += 4) {
        int id = ids[q];
        const float* e = emb + (size_t)id * 32;
        float p = eb[j];
#pragma unroll
        for (int k = 0; k < 32; ++k) p = fmaf(e[k], ew[k * 64 + j], p);
        p = fmaf(rssi[q], ew[32 * 64 + j], p);
        acc += fmaxf(p, 0.f);
    }
    zsh[g][j] = acc;
    __syncthreads();
    if (g == 0) {
        float z = (zsh[0][j] + zsh[1][j] + zsh[2][j] + zsh[3][j]) / (float)NQ;
        zq[j] = z;
        zout[j] = z;
    }
    __syncthreads();
    if (g == 0) {
        float cl = 0.f, cr = 0.f;
        for (int k = 0; k < 64; ++k) {
            float zk = zq[k];
            cl = fmaf(zk, Wl0[(128 + k) * 64 + j], cl);
            cr = fmaf(zk, Wr0[(128 + k) * 64 + j], cr);
        }
        zout[64 + j] = cl;
        zout[128 + j] = cr + b0[j];
    }
}

// ---------------- CSR build: multi-block scan ----------------
__global__ __launch_bounds__(256) void scanA_kernel(const int* __restrict__ deg, int* __restrict__ offs,
                                                    int* __restrict__ bsum, int N)
{
    __shared__ int sh[256];
    int t = threadIdx.x;
    int i = blockIdx.x * 256 + t;
    int v = (i < N) ? deg[i] : 0;
    sh[t] = v;
    __syncthreads();
#pragma unroll
    for (int d = 1; d < 256; d <<= 1) {
        int u = (t >= d) ? sh[t - d] : 0;
        __syncthreads();
        sh[t] += u;
        __syncthreads();
    }
    if (i < N) offs[i] = sh[t] - v;
    if (t == 255) bsum[blockIdx.x] = sh[255];
}

__global__ __launch_bounds__(256) void scanB_kernel(const int* __restrict__ bsum, int* __restrict__ bbase,
                                                    int* __restrict__ offs, unsigned* __restrict__ red,
                                                    int NB, int N)
{
    __shared__ int sh[256];
    int t = threadIdx.x;
    if (t < 4) red[t] = 0u;
    int C = (NB + 255) >> 8;
    int c0 = t * C, c1 = min(c0 + C, NB);
    int s = 0;
    for (int i = c0; i < c1; ++i) s += bsum[i];
    sh[t] = s;
    __syncthreads();
#pragma unroll
    for (int d = 1; d < 256; d <<= 1) {
        int u = (t >= d) ? sh[t - d] : 0;
        __syncthreads();
        sh[t] += u;
        __syncthreads();
    }
    int run = (t > 0) ? sh[t - 1] : 0;
    for (int i = c0; i < c1; ++i) { bbase[i] = run; run += bsum[i]; }
    if (t == 255) offs[N] = sh[255];
}

__global__ __launch_bounds__(256) void scanC_kernel(int* __restrict__ offs, int* __restrict__ cursor,
                                                    const int* __restrict__ bbase, int N)
{
    int i = blockIdx.x * 256 + threadIdx.x;
    if (i < N) {
        int o = offs[i] + bbase[blockIdx.x];
        offs[i] = o;
        cursor[i] = o;
    }
}

// XCD-partitioned scatter (round-2 win): one XCD owns each srcs region.
__global__ __launch_bounds__(256) void scatter_kernel(const int* __restrict__ src, const int* __restrict__ dst,
                                                      int* __restrict__ cursor, int* __restrict__ srcs,
                                                      int E, int N)
{
    const int part = blockIdx.x & 7;
    const int chunk = blockIdx.x >> 3;
    const int npart = (N + 7) >> 3;
    const int lo = part * npart;
    const int hi = min(lo + npart, N);
    const int base = chunk * 4096 + threadIdx.x;
#pragma unroll
    for (int it = 0; it < 16; ++it) {
        int i = base + it * 256;
        if (i < E) {
            int d = dst[i];
            if (d >= lo && d < hi) {
                int p = atomicAdd(&cursor[d], 1);
                srcs[p] = src[i];
            }
        }
    }
}

// ---------------- GEMM (dual out): O1 = A@B1, O2 = A@B2 + add2 ----------------
// 32-row x 128-col tile, 256 thr (thread = 4 rows x 4 cols): 1563 blocks -> ~6 blocks/CU
// (2x the 64-row tile's occupancy; round-8 showed the GEMM is latency-bound at 3/CU).
// A staged ROW-major As[32][36]: staging stores are uniform 4/bank (b128 minimum),
// inner-loop A reads are half-wave same-address broadcasts (free, m136) at LDS latency.
template <int K>
__global__ __launch_bounds__(256) void gemm_kernel(
    const float* __restrict__ A, const float* __restrict__ B1, const float* __restrict__ B2,
    const float* __restrict__ add2,
    float* __restrict__ O1, float* __restrict__ O2, int N)
{
    __shared__ float As[32][36];    // 4.6 KB
    __shared__ float Bs[32][128];   // 16.4 KB

    const int tid = threadIdx.x;
    const int cg = tid & 31;
    const int rg = tid >> 5;        // 8 groups x 4 rows
    const int row0 = blockIdx.x * 32;

    float acc[4][4];
#pragma unroll
    for (int i = 0; i < 4; ++i)
#pragma unroll
        for (int j = 0; j < 4; ++j) acc[i][j] = 0.f;

    for (int kc = 0; kc < K; kc += 32) {
        // stage A chunk: 32 rows x 32 k, one float4 per thread
        {
            int r = tid >> 3;
            int k4 = (tid & 7) << 2;
            int row = row0 + r;
            float4 v = make_float4(0.f, 0.f, 0.f, 0.f);
            if (row < N) v = *(const float4*)(A + (size_t)row * K + kc + k4);
            As[r][k4 + 0] = v.x; As[r][k4 + 1] = v.y; As[r][k4 + 2] = v.z; As[r][k4 + 3] = v.w;
        }
        // stage B chunk: 32 k x 128 c (B1 | B2)
#pragma unroll
        for (int i = 0; i < 4; ++i) {
            int vi = i * 256 + tid;
            int k = vi >> 5;
            int c = (vi & 31) << 2;
            const float* sp = (c < 64) ? (B1 + (size_t)(kc + k) * 64 + c)
                                       : (B2 + (size_t)(kc + k) * 64 + (c - 64));
            *(float4*)&Bs[k][c] = *(const float4*)sp;
        }
        __syncthreads();
#pragma unroll
        for (int k4 = 0; k4 < 32; k4 += 4) {
            float4 a4[4];
#pragma unroll
            for (int i = 0; i < 4; ++i)
                a4[i] = *(const float4*)&As[rg * 4 + i][k4];   // broadcast read
            float4 bv[4];
#pragma unroll
            for (int j = 0; j < 4; ++j)
                bv[j] = *(const float4*)&Bs[k4 + j][cg * 4];
#pragma unroll
            for (int j = 0; j < 4; ++j) {
#pragma unroll
                for (int i = 0; i < 4; ++i) {
                    float av = ((const float*)&a4[i])[j];
                    acc[i][0] = fmaf(av, bv[j].x, acc[i][0]);
                    acc[i][1] = fmaf(av, bv[j].y, acc[i][1]);
                    acc[i][2] = fmaf(av, bv[j].z, acc[i][2]);
                    acc[i][3] = fmaf(av, bv[j].w, acc[i][3]);
                }
            }
        }
        __syncthreads();
    }

    int c0 = cg * 4;
    float* O; int c; const float* addp;
    if (c0 < 64) { O = O1; c = c0; addp = nullptr; }
    else         { O = O2; c = c0 - 64; addp = add2; }
    float4 av = make_float4(0.f, 0.f, 0.f, 0.f);
    if (addp) av = *(const float4*)(addp + c);
#pragma unroll
    for (int i = 0; i < 4; ++i) {
        int row = row0 + rg * 4 + i;
        if (row < N) {
            float4 o;
            o.x = acc[i][0] + av.x; o.y = acc[i][1] + av.y;
            o.z = acc[i][2] + av.z; o.w = acc[i][3] + av.w;
            *(float4*)(O + (size_t)row * 64 + c) = o;
        }
    }
}

// ---------------- aggregation: h = relu(segsum(m)/clip(deg,1) + [deg>0]*cl + r) ----------------
__global__ __launch_bounds__(256) void agg_kernel(
    const float* __restrict__ m, const float* __restrict__ r,
    const int* __restrict__ off, const int* __restrict__ srcs,
    const float* __restrict__ cl, float* __restrict__ hout, int N)
{
    int node = blockIdx.x * 4 + threadIdx.y;
    if (node >= N) return;
    int lane = threadIdx.x;
    int e0 = off[node], e1 = off[node + 1];
    float a[16];
#pragma unroll
    for (int i = 0; i < 16; ++i) a[i] = 0.f;

    for (int base = e0; base < e1; base += 64) {
        int e = base + lane;
        int sv = (e < e1) ? srcs[e] : 0;
        int cnt = min(e1 - base, 64);
        int j = 0;
        for (; j + 16 <= cnt; j += 16) {
#pragma unroll
            for (int u = 0; u < 16; ++u) {
                int s = __shfl(sv, j + u);
                a[u] += m[(size_t)s * 64 + lane];
            }
        }
        for (; j + 4 <= cnt; j += 4) {
#pragma unroll
            for (int u = 0; u < 4; ++u) {
                int s = __shfl(sv, j + u);
                a[u] += m[(size_t)s * 64 + lane];
            }
        }
        for (; j < cnt; ++j) {
            int s = __shfl(sv, j);
            a[0] += m[(size_t)s * 64 + lane];
        }
    }
    float sum = 0.f;
#pragma unroll
    for (int i = 0; i < 16; ++i) sum += a[i];
    int deg = e1 - e0;
    float v = sum / (float)(deg > 0 ? deg : 1) + r[(size_t)node * 64 + lane];
    if (cl != nullptr && deg > 0) v += cl[lane];
    hout[(size_t)node * 64 + lane] = fmaxf(v, 0.f);
}

// ---------------- fused scorer: s = relu(h@w1+b1)@w2 + b2, block max -> atomicMax ----------------
// 32-row tile, same structure as gemm_kernel (K=64, single 64-col output).
__global__ __launch_bounds__(256) void scorer_gemm_kernel(
    const float* __restrict__ A, const float* __restrict__ B1,
    const float* __restrict__ bias, const float* __restrict__ w2, const float* __restrict__ b2,
    float* __restrict__ sbuf, unsigned* __restrict__ red, int N)
{
    __shared__ float As[32][36];
    __shared__ float Bs[32][64];
    __shared__ float smax[256];

    const int tid = threadIdx.x;
    const int cg = tid & 31;
    const int rg = tid >> 5;
    const int row0 = blockIdx.x * 32;

    float acc[4][2];
#pragma unroll
    for (int i = 0; i < 4; ++i) { acc[i][0] = 0.f; acc[i][1] = 0.f; }

    for (int kc = 0; kc < 64; kc += 32) {
        {
            int r = tid >> 3;
            int k4 = (tid & 7) << 2;
            int row = row0 + r;
            float4 v = make_float4(0.f, 0.f, 0.f, 0.f);
            if (row < N) v = *(const float4*)(A + (size_t)row * 64 + kc + k4);
            As[r][k4 + 0] = v.x; As[r][k4 + 1] = v.y; As[r][k4 + 2] = v.z; As[r][k4 + 3] = v.w;
        }
#pragma unroll
        for (int i = 0; i < 2; ++i) {
            int vi = i * 256 + tid;
            int k = vi >> 4;
            int c = (vi & 15) << 2;
            *(float4*)&Bs[k][c] = *(const float4*)(B1 + (size_t)(kc + k) * 64 + c);
        }
        __syncthreads();
#pragma unroll
        for (int k4 = 0; k4 < 32; k4 += 4) {
            float4 a4[4];
#pragma unroll
            for (int i = 0; i < 4; ++i)
                a4[i] = *(const float4*)&As[rg * 4 + i][k4];
            float2 bv[4];
#pragma unroll
            for (int j = 0; j < 4; ++j)
                bv[j] = *(const float2*)&Bs[k4 + j][cg * 2];
#pragma unroll
            for (int j = 0; j < 4; ++j) {
#pragma unroll
                for (int i = 0; i < 4; ++i) {
                    float av = ((const float*)&a4[i])[j];
                    acc[i][0] = fmaf(av, bv[j].x, acc[i][0]);
                    acc[i][1] = fmaf(av, bv[j].y, acc[i][1]);
                }
            }
        }
        __syncthreads();
    }

    float2 av = *(const float2*)(bias + cg * 2);
    float w0 = w2[cg * 2], w1 = w2[cg * 2 + 1];
    float bb = b2[0];
    float svals[4];
#pragma unroll
    for (int i = 0; i < 4; ++i) {
        float t0 = fmaxf(acc[i][0] + av.x, 0.f);
        float t1 = fmaxf(acc[i][1] + av.y, 0.f);
        float p = fmaf(t0, w0, t1 * w1);
#pragma unroll
        for (int d = 16; d >= 1; d >>= 1) p += __shfl_xor(p, d, 64);
        svals[i] = p;
    }
    float smx = -FLT_MAX;
    if (cg == 0) {
#pragma unroll
        for (int i = 0; i < 4; ++i) {
            int row = row0 + rg * 4 + i;
            if (row < N) {
                float s = svals[i] + bb;
                sbuf[row] = s;
                smx = fmaxf(smx, s);
            }
        }
    }
    smax[tid] = smx;
    __syncthreads();
    for (int d = 128; d >= 1; d >>= 1) {
        if (tid < d) smax[tid] = fmaxf(smax[tid], smax[tid + d]);
        __syncthreads();
    }
    if (tid == 0) atomicMax(red, enc_f(smax[0]));
}

// ---------------- softmax reductions ----------------
__global__ __launch_bounds__(256) void sum_kernel(const float* __restrict__ s, const float* __restrict__ pos,
                                                  const unsigned* __restrict__ redmax, float* __restrict__ red, int N)
{
    float mx = dec_f(redmax[0]);
    float se = 0.f, px = 0.f, py = 0.f;
    for (int i = blockIdx.x * blockDim.x + threadIdx.x; i < N; i += gridDim.x * blockDim.x) {
        float e = expf(s[i] - mx);
        se += e;
        px = fmaf(e, pos[2 * i], px);
        py = fmaf(e, pos[2 * i + 1], py);
    }
#pragma unroll
    for (int d = 32; d >= 1; d >>= 1) {
        se += __shfl_xor(se, d, 64);
        px += __shfl_xor(px, d, 64);
        py += __shfl_xor(py, d, 64);
    }
    if ((threadIdx.x & 63) == 0) {
        atomicAdd(&red[1], se);
        atomicAdd(&red[2], px);
        atomicAdd(&red[3], py);
    }
}

__global__ __launch_bounds__(256) void final_kernel(const float* __restrict__ s, const unsigned* __restrict__ redmax,
                                                    const float* __restrict__ red, float* __restrict__ out, int N)
{
    float mx = dec_f(redmax[0]);
    float S = red[1];
    int i = blockIdx.x * blockDim.x + threadIdx.x;
    if (i < N) out[2 + i] = expf(s[i] - mx) / S;
    if (i == 0) {
        out[0] = red[2] / S;
        out[1] = red[3] / S;
    }
}

extern "C" void kernel_launch(void* const* d_in, const int* in_sizes, int n_in,
                              void* d_out, int out_size, void* d_ws, size_t ws_size,
                              hipStream_t stream)
{
    const float* x    = (const float*)d_in[0];
    const float* pos  = (const float*)d_in[1];
    const int*   ei   = (const int*)d_in[2];
    const int*   qids = (const int*)d_in[3];
    const float* qrs  = (const float*)d_in[4];
    const float* emb  = (const float*)d_in[5];
    const float* ew   = (const float*)d_in[6];
    const float* eb   = (const float*)d_in[7];
    const float* Wl0  = (const float*)d_in[8];
    const float* Wr0  = (const float*)d_in[9];
    const float* b0   = (const float*)d_in[10];
    const float* Wl1  = (const float*)d_in[11];
    const float* Wr1  = (const float*)d_in[12];
    const float* b1   = (const float*)d_in[13];
    const float* Wl2  = (const float*)d_in[14];
    const float* Wr2  = (const float*)d_in[15];
    const float* b2   = (const float*)d_in[16];
    const float* sw1  = (const float*)d_in[17];
    const float* sb1  = (const float*)d_in[18];
    const float* sw2  = (const float*)d_in[19];
    const float* sb2  = (const float*)d_in[20];

    const int N  = in_sizes[0] / 128;
    const int E  = in_sizes[2] / 2;
    const int NQ = in_sizes[3];
    const int NB = (N + 255) / 256;

    char* base = (char*)d_ws;
    size_t wsoff = 0;
    auto take = [&](size_t bytes) -> char* {
        char* p = base + wsoff;
        wsoff = (wsoff + bytes + 255) & ~(size_t)255;
        return p;
    };
    int*      deg    = (int*)take((size_t)N * 4);
    int*      offs   = (int*)take((size_t)(N + 1) * 4);
    int*      cursor = (int*)take((size_t)N * 4);
    int*      bsum   = (int*)take((size_t)NB * 4);
    int*      bbase  = (int*)take((size_t)NB * 4);
    int*      srcs   = (int*)take((size_t)E * 4);
    float*    zout   = (float*)take(192 * 4);   // zq[64], cl[64], crb[64]
    unsigned* red    = (unsigned*)take(16);     // [0]=max(enc) [1]=sumexp [2]=px [3]=py
    float*    mbuf   = (float*)take((size_t)N * 64 * 4);
    float*    rbuf   = (float*)take((size_t)N * 64 * 4);
    float*    hbuf   = (float*)take((size_t)N * 64 * 4);
    float*    sbuf   = (float*)take((size_t)N * 4);
    (void)ws_size; (void)n_in; (void)out_size;

    const int* esrc = ei;
    const int* edst = ei + E;

    hipMemsetAsync(deg, 0, (size_t)N * 4, stream);

    int schunks = (E + 4095) / 4096;
    int nCount = schunks * 8;
    enc_count_kernel<<<nCount + 1, 256, 0, stream>>>(edst, deg, E, N, nCount,
                                                     qids, qrs, emb, ew, eb, Wl0, Wr0, b0, zout, NQ);
    scanA_kernel<<<NB, 256, 0, stream>>>(deg, offs, bsum, N);
    scanB_kernel<<<1, 256, 0, stream>>>(bsum, bbase, offs, red, NB, N);
    scanC_kernel<<<NB, 256, 0, stream>>>(offs, cursor, bbase, N);
    scatter_kernel<<<schunks * 8, 256, 0, stream>>>(esrc, edst, cursor, srcs, E, N);

    int gblocks = (N + 31) / 32;
    dim3 ablk(64, 4);
    int ablocks = (N + 3) / 4;

    // layer 0: mbuf = x@Wl0_top, rbuf = x@Wr0_top + (zq@Wr0_bot + b0)
    gemm_kernel<128><<<gblocks, 256, 0, stream>>>(x, Wl0, Wr0, zout + 128, mbuf, rbuf, N);
    agg_kernel<<<ablocks, ablk, 0, stream>>>(mbuf, rbuf, offs, srcs, zout + 64, hbuf, N);
    // layer 1
    gemm_kernel<64><<<gblocks, 256, 0, stream>>>(hbuf, Wl1, Wr1, b1, mbuf, rbuf, N);
    agg_kernel<<<ablocks, ablk, 0, stream>>>(mbuf, rbuf, offs, srcs, nullptr, hbuf, N);
    // layer 2
    gemm_kernel<64><<<gblocks, 256, 0, stream>>>(hbuf, Wl2, Wr2, b2, mbuf, rbuf, N);
    agg_kernel<<<ablocks, ablk, 0, stream>>>(mbuf, rbuf, offs, srcs, nullptr, hbuf, N);
    // fused scorer (writes sbuf + atomicMax into red[0])
    scorer_gemm_kernel<<<gblocks, 256, 0, stream>>>(hbuf, sw1, sb1, sw2, sb2, sbuf, red, N);

    sum_kernel<<<128, 256, 0, stream>>>(sbuf, pos, red, (float*)red, N);
    final_kernel<<<(N + 255) / 256, 256, 0, stream>>>(sbuf, red, (float*)red, (float*)d_out, N);
}